// Round 3
// baseline (114.220 us; speedup 1.0000x reference)
//
#include <hip/hip_runtime.h>

// LIF layer: input (T=256, B=32, N=4096) fp32. Recurrence over T; B*N columns
// independent. Outputs concatenated: spikes[T][B*N] (0/1 f32), volts[T][B*N].
//
// R2 structure: R0's float4-per-thread layout (proven 82 µs @ 4.9 TB/s), but
// the T-loop is batched 16-deep: all 16 independent float4 loads are issued
// into a statically-indexed register array BEFORE any compute/store. This
// pins in-flight read bytes at 16 KB/wave x 2 waves = 32 KB/CU, above the
// Little's-law target (~22 KB/CU for 6.3 TB/s @ ~900 ns HBM latency).
// R1's regression (scalar + nontemporal + ptr-increment) is fully reverted.

#define T_STEPS 256
#define BN      (32 * 4096)      // 131072
#define COLS    (BN / 4)         // 32768 float4 columns
#define TB      16               // T-batch depth (loads in flight per thread)

__global__ __launch_bounds__(128) void lif_kernel(
    const float4* __restrict__ in,
    float* __restrict__ out,
    const float* __restrict__ decay_p,
    const float* __restrict__ vth_p,
    const float* __restrict__ vreset_p)
{
    const int col = blockIdx.x * 128 + threadIdx.x;   // 0..COLS-1

    const float decay   = *decay_p;
    const float v_th    = *vth_p;
    const float v_reset = *vreset_p;

    float4* __restrict__ spikes = (float4*)out;                            // [T][COLS]
    float4* __restrict__ volts  = (float4*)(out + (size_t)T_STEPS * BN);   // [T][COLS]

    const float4* ip = in     + col;
    float4*       sp = spikes + col;
    float4*       vp = volts  + col;

    float vx = 0.f, vy = 0.f, vz = 0.f, vw = 0.f;

    for (int tb = 0; tb < T_STEPS; tb += TB) {
        float4 I[TB];
        #pragma unroll
        for (int u = 0; u < TB; ++u)
            I[u] = ip[(size_t)(tb + u) * COLS];     // 16 loads issued back-to-back

        #pragma unroll
        for (int u = 0; u < TB; ++u) {
            const size_t off = (size_t)(tb + u) * COLS;
            float4 s, v;
            float n;
            // decay*V + I with SEPARATE mul/add roundings (match numpy; no FMA).
            n = __fadd_rn(__fmul_rn(decay, vx), I[u].x);
            s.x = (n >= v_th) ? 1.f : 0.f;  vx = (n >= v_th) ? v_reset : n;  v.x = vx;

            n = __fadd_rn(__fmul_rn(decay, vy), I[u].y);
            s.y = (n >= v_th) ? 1.f : 0.f;  vy = (n >= v_th) ? v_reset : n;  v.y = vy;

            n = __fadd_rn(__fmul_rn(decay, vz), I[u].z);
            s.z = (n >= v_th) ? 1.f : 0.f;  vz = (n >= v_th) ? v_reset : n;  v.z = vz;

            n = __fadd_rn(__fmul_rn(decay, vw), I[u].w);
            s.w = (n >= v_th) ? 1.f : 0.f;  vw = (n >= v_th) ? v_reset : n;  v.w = vw;

            sp[off] = s;
            vp[off] = v;
        }
    }
}

extern "C" void kernel_launch(void* const* d_in, const int* in_sizes, int n_in,
                              void* d_out, int out_size, void* d_ws, size_t ws_size,
                              hipStream_t stream) {
    const float4* in      = (const float4*)d_in[0];
    const float*  decay_p = (const float*)d_in[1];
    const float*  vth_p   = (const float*)d_in[2];
    const float*  vrst_p  = (const float*)d_in[3];
    float*        out     = (float*)d_out;

    dim3 grid(COLS / 128);   // 256 blocks -> 1 block (2 waves) per CU
    dim3 block(128);
    hipLaunchKernelGGL(lif_kernel, grid, block, 0, stream,
                       in, out, decay_p, vth_p, vrst_p);
}

// Round 4
// 82.285 us; speedup vs baseline: 1.3881x; 1.3881x over previous
//
#include <hip/hip_runtime.h>

// LIF layer: input (T=256, B=32, N=4096) fp32. Recurrence over T; B*N columns
// independent. Outputs concatenated: spikes[T][B*N] (0/1 f32), volts[T][B*N].
//
// R3 structure: identical to R0 (best so far, 82 µs) EXCEPT per-thread width
// float4 -> float2. 65536 threads = 1024 waves = 4 waves/CU: one wave per
// SIMD (R0 left 2 of 4 SIMDs idle). Coalescing unchanged (512 B/instr).
// Indexed addressing, no nontemporal, compiler-scheduled unroll 8 — the
// explicit 16-deep load batch of R2 (114 µs, compiler serialized the batch)
// is fully reverted.

#define T_STEPS 256
#define BN      (32 * 4096)      // 131072
#define COLS2   (BN / 2)         // 65536 float2 columns

__global__ __launch_bounds__(256) void lif_kernel(
    const float2* __restrict__ in,
    float* __restrict__ out,
    const float* __restrict__ decay_p,
    const float* __restrict__ vth_p,
    const float* __restrict__ vreset_p)
{
    const int col = blockIdx.x * 256 + threadIdx.x;   // 0..COLS2-1

    const float decay   = *decay_p;
    const float v_th    = *vth_p;
    const float v_reset = *vreset_p;

    float2* __restrict__ spikes = (float2*)out;                            // [T][COLS2]
    float2* __restrict__ volts  = (float2*)(out + (size_t)T_STEPS * BN);   // [T][COLS2]

    const float2* ip = in     + col;
    float2*       sp = spikes + col;
    float2*       vp = volts  + col;

    float vx = 0.f, vy = 0.f;

    #pragma unroll 8
    for (int t = 0; t < T_STEPS; ++t) {
        float2 I = ip[(size_t)t * COLS2];
        float2 s, v;
        float n;
        // decay*V + I with SEPARATE mul/add roundings (match numpy; no FMA).
        n = __fadd_rn(__fmul_rn(decay, vx), I.x);
        s.x = (n >= v_th) ? 1.f : 0.f;  vx = (n >= v_th) ? v_reset : n;  v.x = vx;

        n = __fadd_rn(__fmul_rn(decay, vy), I.y);
        s.y = (n >= v_th) ? 1.f : 0.f;  vy = (n >= v_th) ? v_reset : n;  v.y = vy;

        sp[(size_t)t * COLS2] = s;
        vp[(size_t)t * COLS2] = v;
    }
}

extern "C" void kernel_launch(void* const* d_in, const int* in_sizes, int n_in,
                              void* d_out, int out_size, void* d_ws, size_t ws_size,
                              hipStream_t stream) {
    const float2* in      = (const float2*)d_in[0];
    const float*  decay_p = (const float*)d_in[1];
    const float*  vth_p   = (const float*)d_in[2];
    const float*  vrst_p  = (const float*)d_in[3];
    float*        out     = (float*)d_out;

    dim3 grid(COLS2 / 256);   // 256 blocks -> 1 block (4 waves) per CU
    dim3 block(256);
    hipLaunchKernelGGL(lif_kernel, grid, block, 0, stream,
                       in, out, decay_p, vth_p, vrst_p);
}

// Round 6
// 62.653 us; speedup vs baseline: 1.8231x; 1.3133x over previous
//
#include <hip/hip_runtime.h>

// LIF layer: input (T=256, B=32, N=4096) fp32. Recurrence over T; B*N columns
// independent. Outputs concatenated: spikes[T][B*N] (0/1 f32), volts[T][B*N].
//
// R5 = R4's intent with a compile fix: __builtin_nontemporal_store requires a
// native clang vector type, so use float ext_vector_type(2) instead of HIP's
// float2 struct. Structure otherwise identical to R3 (82 µs, 4 waves/CU,
// float2-width per thread): nontemporal (evict-first) stores on the two
// output streams so the 268 MB write stream doesn't thrash the 256 MB L3 out
// of holding the 134 MB input between graph replays. Loads stay cached.

#define T_STEPS 256
#define BN      (32 * 4096)      // 131072
#define COLS2   (BN / 2)         // 65536 two-float columns

typedef float v2f __attribute__((ext_vector_type(2)));

__global__ __launch_bounds__(256) void lif_kernel(
    const v2f* __restrict__ in,
    float* __restrict__ out,
    const float* __restrict__ decay_p,
    const float* __restrict__ vth_p,
    const float* __restrict__ vreset_p)
{
    const int col = blockIdx.x * 256 + threadIdx.x;   // 0..COLS2-1

    const float decay   = *decay_p;
    const float v_th    = *vth_p;
    const float v_reset = *vreset_p;

    v2f* __restrict__ spikes = (v2f*)out;                            // [T][COLS2]
    v2f* __restrict__ volts  = (v2f*)(out + (size_t)T_STEPS * BN);   // [T][COLS2]

    const v2f* ip = in     + col;
    v2f*       sp = spikes + col;
    v2f*       vp = volts  + col;

    float vx = 0.f, vy = 0.f;

    #pragma unroll 8
    for (int t = 0; t < T_STEPS; ++t) {
        v2f I = ip[(size_t)t * COLS2];
        v2f s, v;
        float n;
        // decay*V + I with SEPARATE mul/add roundings (match numpy; no FMA).
        n = __fadd_rn(__fmul_rn(decay, vx), I.x);
        s.x = (n >= v_th) ? 1.f : 0.f;  vx = (n >= v_th) ? v_reset : n;  v.x = vx;

        n = __fadd_rn(__fmul_rn(decay, vy), I.y);
        s.y = (n >= v_th) ? 1.f : 0.f;  vy = (n >= v_th) ? v_reset : n;  v.y = vy;

        __builtin_nontemporal_store(s, &sp[(size_t)t * COLS2]);
        __builtin_nontemporal_store(v, &vp[(size_t)t * COLS2]);
    }
}

extern "C" void kernel_launch(void* const* d_in, const int* in_sizes, int n_in,
                              void* d_out, int out_size, void* d_ws, size_t ws_size,
                              hipStream_t stream) {
    const v2f*   in      = (const v2f*)d_in[0];
    const float* decay_p = (const float*)d_in[1];
    const float* vth_p   = (const float*)d_in[2];
    const float* vrst_p  = (const float*)d_in[3];
    float*       out     = (float*)d_out;

    dim3 grid(COLS2 / 256);   // 256 blocks -> 1 block (4 waves) per CU
    dim3 block(256);
    hipLaunchKernelGGL(lif_kernel, grid, block, 0, stream,
                       in, out, decay_p, vth_p, vrst_p);
}